// Round 1
// baseline (391.253 us; speedup 1.0000x reference)
//
#include <hip/hip_runtime.h>

typedef __attribute__((ext_vector_type(8))) short bf16x8;
typedef __attribute__((ext_vector_type(4))) float f32x4;
typedef __attribute__((ext_vector_type(4))) int int4v;
typedef __attribute__((ext_vector_type(4))) unsigned short us4;

#define LOG2E 1.4426950408889634f

__device__ __forceinline__ unsigned short f2b(float f){
  unsigned u = __builtin_bit_cast(unsigned, f);
  u = (u + 0x7fffu + ((u >> 16) & 1u)) >> 16;
  return (unsigned short)u;
}

__device__ __forceinline__ f32x4 mfma16(bf16x8 a, bf16x8 b, f32x4 c){
  return __builtin_amdgcn_mfma_f32_16x16x32_bf16(a, b, c, 0, 0, 0);
}

// ---------------- cast fp32 -> bf16 (vectorized) ----------------
__global__ __launch_bounds__(256) void cast_bf16_kernel(const float4* __restrict__ in,
                                                        us4* __restrict__ out, int n4){
  int i = blockIdx.x * 256 + threadIdx.x;
  int stride = gridDim.x * 256;
  for (; i < n4; i += stride){
    float4 v = in[i];
    us4 o; o.x = f2b(v.x); o.y = f2b(v.y); o.z = f2b(v.z); o.w = f2b(v.w);
    out[i] = o;
  }
}

// ---------------- transpose + cast: in[R][C] fp32 -> out[C][R] bf16 ----------------
__global__ __launch_bounds__(256) void transpose_cast_kernel(const float* __restrict__ in,
                                                             unsigned short* __restrict__ out,
                                                             int R, int C){
  __shared__ float tile[64][65];
  const int tid = threadIdx.x;
  const int c0 = blockIdx.x * 64, r0 = blockIdx.y * 64;
#pragma unroll
  for (int p = 0; p < 4; p++){
    int idx = p * 1024 + tid * 4;
    int rr = idx >> 6, cc = idx & 63;
    float4 v = *(const float4*)(in + (size_t)(r0 + rr) * C + (c0 + cc));
    tile[rr][cc+0] = v.x; tile[rr][cc+1] = v.y; tile[rr][cc+2] = v.z; tile[rr][cc+3] = v.w;
  }
  __syncthreads();
#pragma unroll
  for (int p = 0; p < 4; p++){
    int idx = p * 1024 + tid * 4;
    int crow = idx >> 6, rcol = idx & 63;
    us4 o;
    o.x = f2b(tile[rcol+0][crow]); o.y = f2b(tile[rcol+1][crow]);
    o.z = f2b(tile[rcol+2][crow]); o.w = f2b(tile[rcol+3][crow]);
    *(us4*)(out + (size_t)(c0 + crow) * R + (r0 + rcol)) = o;
  }
}

// ---------------- bf16 GEMM: C[M][N] = A[M][K] * BT[N][K]^T + bias ----------------
// MODE 0: epilogue scatters q (scaled), k as [B,H,L,E] and v transposed as [B,H,E,L]
// MODE 1: epilogue writes fp32 out[M][N] + bias
template<int MODE>
__global__ __launch_bounds__(256, 2) void gemm_kernel(
    const unsigned short* __restrict__ A,
    const unsigned short* __restrict__ BT,
    const float* __restrict__ bias,
    unsigned short* __restrict__ qb,
    unsigned short* __restrict__ kb,
    unsigned short* __restrict__ vtb,
    float* __restrict__ outp)
{
  constexpr int K = 2048;
  constexpr int NT = K / 64;
  __shared__ short lA[2][128 * 64];
  __shared__ short lB[2][128 * 64];
  const int tid = threadIdx.x, lane = tid & 63, wid = tid >> 6;
  const int l16 = lane & 15, lhi = lane >> 4;
  const int wr = wid >> 1, wc = wid & 1;
  const int bm = blockIdx.x, bn = blockIdx.y;

  const unsigned short* Abase = A + (size_t)bm * 128 * K;
  const unsigned short* Bbase = BT + (size_t)bn * 128 * K;

  int4v areg[4], breg[4];

  auto stage_load = [&](int kt){
#pragma unroll
    for (int i = 0; i < 4; i++){
      int c = tid + 256 * i;
      int row = c >> 3; int off8 = (c & 7) * 8;
      areg[i] = *(const int4v*)(Abase + (size_t)row * K + kt * 64 + off8);
      breg[i] = *(const int4v*)(Bbase + (size_t)row * K + kt * 64 + off8);
    }
  };
  auto stage_write = [&](int buf){
#pragma unroll
    for (int i = 0; i < 4; i++){
      int c = tid + 256 * i;
      int row = c >> 3;
      int byte = (row * 128 + (c & 7) * 16) ^ ((row & 7) << 4);
      *(int4v*)((char*)lA[buf] + byte) = areg[i];
      *(int4v*)((char*)lB[buf] + byte) = breg[i];
    }
  };

  f32x4 acc[4][4];
  f32x4 z = {0.f, 0.f, 0.f, 0.f};
#pragma unroll
  for (int i = 0; i < 4; i++)
#pragma unroll
    for (int j = 0; j < 4; j++) acc[i][j] = z;

  stage_load(0); stage_write(0); __syncthreads();
  int cur = 0;
  for (int kt = 0; kt < NT; ++kt){
    if (kt + 1 < NT) stage_load(kt + 1);
#pragma unroll
    for (int kk = 0; kk < 2; kk++){
      bf16x8 af[4], bfr[4];
#pragma unroll
      for (int mf = 0; mf < 4; mf++){
        int row = wr * 64 + mf * 16 + l16;
        int byte = (row * 128 + kk * 64 + lhi * 16) ^ ((row & 7) << 4);
        af[mf] = *(const bf16x8*)((const char*)lA[cur] + byte);
      }
#pragma unroll
      for (int nf = 0; nf < 4; nf++){
        int row = wc * 64 + nf * 16 + l16;
        int byte = (row * 128 + kk * 64 + lhi * 16) ^ ((row & 7) << 4);
        bfr[nf] = *(const bf16x8*)((const char*)lB[cur] + byte);
      }
#pragma unroll
      for (int mf = 0; mf < 4; mf++)
#pragma unroll
        for (int nf = 0; nf < 4; nf++)
          acc[mf][nf] = mfma16(af[mf], bfr[nf], acc[mf][nf]);
    }
    __syncthreads();
    if (kt + 1 < NT) stage_write(cur ^ 1);
    __syncthreads();
    cur ^= 1;
  }

  const int row0 = bm * 128 + wr * 64;
  const int col0 = bn * 128 + wc * 64;
  if (MODE == 0){
#pragma unroll
    for (int nf = 0; nf < 4; nf++){
      int colb = col0 + nf * 16;
      float bv = bias[colb + l16];
      int which = colb >> 11;
      int h = (colb >> 7) & 15;
      int e = (colb & 127) + l16;
#pragma unroll
      for (int mf = 0; mf < 4; mf++){
#pragma unroll
        for (int r = 0; r < 4; r++){
          int row = row0 + mf * 16 + lhi * 4 + r;
          int b = row >> 11, t = row & 2047;
          float v = acc[mf][nf][r] + bv;
          size_t bh = (size_t)(b * 16 + h);
          if (which == 0)      qb[(bh * 2048 + t) * 128 + e] = f2b(v * 0.08838834764831845f);
          else if (which == 1) kb[(bh * 2048 + t) * 128 + e] = f2b(v);
          else                 vtb[(bh * 128 + e) * 2048 + t] = f2b(v);
        }
      }
    }
  } else {
#pragma unroll
    for (int nf = 0; nf < 4; nf++){
      int col = col0 + nf * 16 + l16;
      float bv = bias[col];
#pragma unroll
      for (int mf = 0; mf < 4; mf++){
#pragma unroll
        for (int r = 0; r < 4; r++){
          int row = row0 + mf * 16 + lhi * 4 + r;
          outp[(size_t)row * 2048 + col] = acc[mf][nf][r] + bv;
        }
      }
    }
  }
}

// ---------------- flash attention (non-causal), q pre-scaled ----------------
// grid: (L/64, B*H); 4 waves, each owns 16 q rows. K/V tiles of 64 keys, dbuf.
__global__ __launch_bounds__(256, 2) void attn_kernel(
    const unsigned short* __restrict__ q_buf,
    const unsigned short* __restrict__ k_buf,
    const unsigned short* __restrict__ vt_buf,
    unsigned short* __restrict__ attn_out)
{
  constexpr int L = 2048, E = 128;
  __shared__ short lK[2][64 * 128];
  __shared__ short lVT[2][128 * 64];
  __shared__ short lP[4][16 * 64];
  const int tid = threadIdx.x, lane = tid & 63, wid = tid >> 6;
  const int l16 = lane & 15, lhi = lane >> 4;
  const int bh = blockIdx.y;
  const int qbase = blockIdx.x * 64;
  const unsigned short* qp = q_buf + (size_t)bh * L * E;
  const unsigned short* kp = k_buf + (size_t)bh * L * E;
  const unsigned short* vp = vt_buf + (size_t)bh * E * L;

  bf16x8 qf[4];
  {
    int qrow = qbase + wid * 16 + l16;
#pragma unroll
    for (int kk = 0; kk < 4; kk++)
      qf[kk] = *(const bf16x8*)(qp + (size_t)qrow * E + kk * 32 + lhi * 8);
  }

  f32x4 z = {0.f, 0.f, 0.f, 0.f};
  f32x4 oacc[8];
#pragma unroll
  for (int i = 0; i < 8; i++) oacc[i] = z;
  float mrow[4] = {-1e30f, -1e30f, -1e30f, -1e30f};
  float lsum[4] = {0.f, 0.f, 0.f, 0.f};

  int4v kreg[4], vreg[4];
  auto stage_load = [&](int kt){
#pragma unroll
    for (int i = 0; i < 4; i++){
      int c = tid + 256 * i;
      { int row = c >> 4; int off = (c & 15) * 8;
        kreg[i] = *(const int4v*)(kp + (size_t)(kt * 64 + row) * E + off); }
      { int row = c >> 3; int off = (c & 7) * 8;
        vreg[i] = *(const int4v*)(vp + (size_t)row * L + kt * 64 + off); }
    }
  };
  auto stage_write = [&](int buf){
#pragma unroll
    for (int i = 0; i < 4; i++){
      int c = tid + 256 * i;
      { int row = c >> 4; int byte = (row * 256 + (c & 15) * 16) ^ ((row & 7) << 4);
        *(int4v*)((char*)lK[buf] + byte) = kreg[i]; }
      { int row = c >> 3; int byte = (row * 128 + (c & 7) * 16) ^ ((row & 7) << 4);
        *(int4v*)((char*)lVT[buf] + byte) = vreg[i]; }
    }
  };

  stage_load(0); stage_write(0); __syncthreads();
  int cur = 0;
  for (int kt = 0; kt < L / 64; ++kt){
    if (kt + 1 < L / 64) stage_load(kt + 1);

    // S = Q K^T  (q pre-scaled by 1/sqrt(E))
    f32x4 sf[4];
#pragma unroll
    for (int nf = 0; nf < 4; nf++) sf[nf] = z;
#pragma unroll
    for (int kk = 0; kk < 4; kk++){
#pragma unroll
      for (int nf = 0; nf < 4; nf++){
        int key = nf * 16 + l16;
        int byte = (key * 256 + kk * 64 + lhi * 16) ^ ((key & 7) << 4);
        bf16x8 kb8 = *(const bf16x8*)((const char*)lK[cur] + byte);
        sf[nf] = mfma16(qf[kk], kb8, sf[nf]);
      }
    }

    // online softmax (rows live in 16-lane groups)
    float tmax[4];
#pragma unroll
    for (int r = 0; r < 4; r++)
      tmax[r] = fmaxf(fmaxf(sf[0][r], sf[1][r]), fmaxf(sf[2][r], sf[3][r]));
#pragma unroll
    for (int off = 1; off < 16; off <<= 1){
#pragma unroll
      for (int r = 0; r < 4; r++)
        tmax[r] = fmaxf(tmax[r], __shfl_xor(tmax[r], off, 64));
    }
    float alpha[4], mnew[4], rsum[4];
#pragma unroll
    for (int r = 0; r < 4; r++){
      mnew[r] = fmaxf(mrow[r], tmax[r]);
      alpha[r] = __builtin_exp2f((mrow[r] - mnew[r]) * LOG2E);
      rsum[r] = 0.f;
    }
#pragma unroll
    for (int nf = 0; nf < 4; nf++){
#pragma unroll
      for (int r = 0; r < 4; r++){
        float p = __builtin_exp2f((sf[nf][r] - mnew[r]) * LOG2E);
        rsum[r] += p;
        int row = lhi * 4 + r;
        int byte = (row * 128 + (nf * 16 + l16) * 2) ^ ((row & 7) << 4);
        *(short*)((char*)lP[wid] + byte) = (short)f2b(p);
      }
    }
#pragma unroll
    for (int off = 1; off < 16; off <<= 1){
#pragma unroll
      for (int r = 0; r < 4; r++)
        rsum[r] += __shfl_xor(rsum[r], off, 64);
    }
#pragma unroll
    for (int r = 0; r < 4; r++){
      lsum[r] = lsum[r] * alpha[r] + rsum[r];
      mrow[r] = mnew[r];
    }
#pragma unroll
    for (int ne = 0; ne < 8; ne++)
#pragma unroll
      for (int r = 0; r < 4; r++)
        oacc[ne][r] *= alpha[r];

    // PV: out += P @ V   (P from per-wave LDS, V^T tile rows are e)
    bf16x8 pa[2];
#pragma unroll
    for (int kk2 = 0; kk2 < 2; kk2++){
      int row = l16;
      int byte = (row * 128 + kk2 * 64 + lhi * 16) ^ ((row & 7) << 4);
      pa[kk2] = *(const bf16x8*)((const char*)lP[wid] + byte);
    }
#pragma unroll
    for (int ne = 0; ne < 8; ne++){
#pragma unroll
      for (int kk2 = 0; kk2 < 2; kk2++){
        int e = ne * 16 + l16;
        int byte = (e * 128 + kk2 * 64 + lhi * 16) ^ ((e & 7) << 4);
        bf16x8 vb = *(const bf16x8*)((const char*)lVT[cur] + byte);
        oacc[ne] = mfma16(pa[kk2], vb, oacc[ne]);
      }
    }

    __syncthreads();
    if (kt + 1 < L / 64) stage_write(cur ^ 1);
    __syncthreads();
    cur ^= 1;
  }

  const int b = bh >> 4, h = bh & 15;
#pragma unroll
  for (int ne = 0; ne < 8; ne++){
#pragma unroll
    for (int r = 0; r < 4; r++){
      int row = qbase + wid * 16 + lhi * 4 + r;
      float v = oacc[ne][r] / lsum[r];
      attn_out[((size_t)(b * L + row)) * 2048 + h * 128 + ne * 16 + l16] = f2b(v);
    }
  }
}

extern "C" void kernel_launch(void* const* d_in, const int* in_sizes, int n_in,
                              void* d_out, int out_size, void* d_ws, size_t ws_size,
                              hipStream_t stream) {
  const float* x     = (const float*)d_in[0];
  const float* w_qkv = (const float*)d_in[1];
  const float* b_qkv = (const float*)d_in[2];
  const float* w_out = (const float*)d_in[3];
  const float* b_out = (const float*)d_in[4];
  float* out = (float*)d_out;

  unsigned short* ws = (unsigned short*)d_ws;
  unsigned short* xb    = ws;                               // 4096*2048
  unsigned short* wqkvT = xb    + (size_t)4096 * 2048;      // 6144*2048
  unsigned short* woutT = wqkvT + (size_t)6144 * 2048;      // 2048*2048
  unsigned short* qb    = woutT + (size_t)2048 * 2048;      // [2,16,2048,128]
  unsigned short* kb    = qb    + (size_t)2 * 16 * 2048 * 128;
  unsigned short* vtb   = kb    + (size_t)2 * 16 * 2048 * 128;  // [2,16,128,2048]
  unsigned short* attnb = vtb   + (size_t)2 * 16 * 2048 * 128;  // 4096*2048

  cast_bf16_kernel<<<2048, 256, 0, stream>>>((const float4*)x, (us4*)xb, (4096 * 2048) / 4);
  transpose_cast_kernel<<<dim3(96, 32), 256, 0, stream>>>(w_qkv, wqkvT, 2048, 6144);
  transpose_cast_kernel<<<dim3(32, 32), 256, 0, stream>>>(w_out, woutT, 2048, 2048);
  gemm_kernel<0><<<dim3(32, 48), 256, 0, stream>>>(xb, wqkvT, b_qkv, qb, kb, vtb, nullptr);
  attn_kernel<<<dim3(32, 32), 256, 0, stream>>>(qb, kb, vtb, attnb);
  gemm_kernel<1><<<dim3(32, 16), 256, 0, stream>>>(attnb, woutT, b_out, nullptr, nullptr, nullptr, out);
}